// Round 1
// baseline (324.237 us; speedup 1.0000x reference)
//
#include <hip/hip_runtime.h>
#include <hip/hip_bf16.h>
#include <math.h>

// Problem constants (fixed by setup_inputs)
#define Bn 4
#define Hn 8
#define Sn 4096
#define Dn 256
#define Mn 256
#define BSn (Bn*Sn)          // 16384 rows
#define LN_EPS 1e-5f
#define KEPS 1e-4f
#define DATA_NORM 0.25f      // 256^-0.25
#define DN2 0.0625f          // 256^-0.5
#define RATIO 0.0625f        // 256^-0.5

// ---------- block reductions (256 threads = 4 waves of 64) ----------
__device__ __forceinline__ float blockReduceSum(float v) {
    __shared__ float buf[4];
    #pragma unroll
    for (int o = 32; o > 0; o >>= 1) v += __shfl_down(v, o);
    __syncthreads();                    // protect buf reuse across calls
    if ((threadIdx.x & 63) == 0) buf[threadIdx.x >> 6] = v;
    __syncthreads();
    return buf[0] + buf[1] + buf[2] + buf[3];
}

__device__ __forceinline__ float blockReduceMax(float v) {
    __shared__ float buf[4];
    #pragma unroll
    for (int o = 32; o > 0; o >>= 1) v = fmaxf(v, __shfl_down(v, o));
    __syncthreads();
    if ((threadIdx.x & 63) == 0) buf[threadIdx.x >> 6] = v;
    __syncthreads();
    return fmaxf(fmaxf(buf[0], buf[1]), fmaxf(buf[2], buf[3]));
}

// ---------- 1. LayerNorm + diag ----------
__global__ __launch_bounds__(256) void k_ln(const float* __restrict__ X,
                                            const float* __restrict__ gamma,
                                            const float* __restrict__ beta,
                                            float* __restrict__ XN,
                                            float* __restrict__ diag) {
    const int row = blockIdx.x, t = threadIdx.x;
    float x = X[row * Dn + t];
    float mean = blockReduceSum(x) * (1.0f / Dn);
    float v = x - mean;
    float var = blockReduceSum(v * v) * (1.0f / Dn);
    float rs = rsqrtf(var + LN_EPS);
    float xn = v * rs * gamma[t] + beta[t];
    XN[row * Dn + t] = xn;
    float d2 = blockReduceSum(xn * xn);
    if (t == 0) diag[row] = 0.5f * DN2 * d2;   // 0.03125 * sum(xn^2)
}

// ---------- 2. pd = DATA_NORM * xn @ proj^T   [BS,256] ----------
__global__ __launch_bounds__(256) void k_gemm_pd(const float* __restrict__ XN,
                                                 const float* __restrict__ P,
                                                 float* __restrict__ PD) {
    __shared__ float As[16][68];   // [k][row]
    __shared__ float Bs[16][68];   // [k][m]
    const int r0 = blockIdx.x * 64, m0 = blockIdx.y * 64;
    const int t = threadIdx.x;
    const int tx = t & 15, ty = t >> 4;          // tx: n dir, ty: m(row) dir
    const int lr = t >> 2, lc = (t & 3) * 4;     // loader: 64 rows x 4 col-groups
    float acc[4][4] = {};
    for (int kt = 0; kt < Dn; kt += 16) {
        float4 a4 = *(const float4*)&XN[(r0 + lr) * Dn + kt + lc];
        float4 b4 = *(const float4*)&P[(m0 + lr) * Dn + kt + lc];
        __syncthreads();
        As[lc + 0][lr] = a4.x; As[lc + 1][lr] = a4.y; As[lc + 2][lr] = a4.z; As[lc + 3][lr] = a4.w;
        Bs[lc + 0][lr] = b4.x; Bs[lc + 1][lr] = b4.y; Bs[lc + 2][lr] = b4.z; Bs[lc + 3][lr] = b4.w;
        __syncthreads();
        #pragma unroll
        for (int kk = 0; kk < 16; kk++) {
            float4 av = *(float4*)&As[kk][ty * 4];
            float4 bv = *(float4*)&Bs[kk][tx * 4];
            float ar[4] = {av.x, av.y, av.z, av.w};
            float br[4] = {bv.x, bv.y, bv.z, bv.w};
            #pragma unroll
            for (int i = 0; i < 4; i++)
                #pragma unroll
                for (int j = 0; j < 4; j++)
                    acc[i][j] += ar[i] * br[j];
        }
    }
    #pragma unroll
    for (int i = 0; i < 4; i++) {
        float4 o = make_float4(DATA_NORM * acc[i][0], DATA_NORM * acc[i][1],
                               DATA_NORM * acc[i][2], DATA_NORM * acc[i][3]);
        *(float4*)&PD[(r0 + ty * 4 + i) * Mn + m0 + tx * 4] = o;
    }
}

// ---------- 3. per-row max and per-batch max ----------
__global__ __launch_bounds__(256) void k_rowmax(const float* __restrict__ PD,
                                                float* __restrict__ mxq) {
    const int row = blockIdx.x;
    float m = blockReduceMax(PD[row * Mn + threadIdx.x]);
    if (threadIdx.x == 0) mxq[row] = m;
}

__global__ __launch_bounds__(256) void k_batchmax(const float* __restrict__ mxq,
                                                  float* __restrict__ mxk) {
    const int b = blockIdx.x;
    float m = -INFINITY;
    for (int i = threadIdx.x; i < Sn; i += 256) m = fmaxf(m, mxq[b * Sn + i]);
    m = blockReduceMax(m);
    if (threadIdx.x == 0) mxk[b] = m;
}

// ---------- 4. ctx[b] = K^T @ V (split-S, atomic) + ksum ----------
__global__ __launch_bounds__(256) void k_ctx(const float* __restrict__ PD,
                                             const float* __restrict__ XN,
                                             const float* __restrict__ diag,
                                             const float* __restrict__ mxk,
                                             float* __restrict__ CTX,
                                             float* __restrict__ KSUM) {
    // grid: x = 8 s-chunks, y = 16 (mtile*4 + dtile), z = 4 batches
    const int b = blockIdx.z;
    const int m0 = (blockIdx.y >> 2) * 64, d0 = (blockIdx.y & 3) * 64;
    const int s0base = blockIdx.x * (Sn / 8);
    __shared__ float Ks[16][68];   // [s][m]
    __shared__ float Vs[16][68];   // [s][d]
    const int t = threadIdx.x, tx = t & 15, ty = t >> 4;
    const int sr = t >> 4, c4 = (t & 15) * 4;   // loader: 16 s-rows x 16 col-groups
    float acc[4][4] = {};
    float ks_local = 0.0f;
    const float mk = mxk[b];
    const bool do_ksum = ((blockIdx.y & 3) == 0) && (t < 64);
    for (int sc = 0; sc < Sn / 8; sc += 16) {
        const int srow = b * Sn + s0base + sc + sr;
        float4 p4 = *(const float4*)&PD[srow * Mn + m0 + c4];
        float4 v4 = *(const float4*)&XN[srow * Dn + d0 + c4];
        float dg = diag[srow];
        float4 k4;
        k4.x = RATIO * (expf(p4.x - dg - mk) + KEPS);
        k4.y = RATIO * (expf(p4.y - dg - mk) + KEPS);
        k4.z = RATIO * (expf(p4.z - dg - mk) + KEPS);
        k4.w = RATIO * (expf(p4.w - dg - mk) + KEPS);
        __syncthreads();
        *(float4*)&Ks[sr][c4] = k4;
        *(float4*)&Vs[sr][c4] = v4;
        __syncthreads();
        if (do_ksum) {
            #pragma unroll
            for (int kk = 0; kk < 16; kk++) ks_local += Ks[kk][t];
        }
        #pragma unroll
        for (int kk = 0; kk < 16; kk++) {
            float4 av = *(float4*)&Ks[kk][ty * 4];
            float4 bv = *(float4*)&Vs[kk][tx * 4];
            float ar[4] = {av.x, av.y, av.z, av.w};
            float br[4] = {bv.x, bv.y, bv.z, bv.w};
            #pragma unroll
            for (int i = 0; i < 4; i++)
                #pragma unroll
                for (int j = 0; j < 4; j++)
                    acc[i][j] += ar[i] * br[j];
        }
    }
    #pragma unroll
    for (int i = 0; i < 4; i++)
        #pragma unroll
        for (int j = 0; j < 4; j++)
            atomicAdd(&CTX[b * (Mn * Dn) + (m0 + ty * 4 + i) * Dn + d0 + tx * 4 + j], acc[i][j]);
    if (do_ksum) atomicAdd(&KSUM[b * Mn + m0 + t], ks_local);
}

// ---------- 5. d_inv ----------
__global__ __launch_bounds__(256) void k_dinv(const float* __restrict__ PD,
                                              const float* __restrict__ diag,
                                              const float* __restrict__ mxq,
                                              const float* __restrict__ KSUM,
                                              float* __restrict__ dinv) {
    const int row = blockIdx.x, t = threadIdx.x;
    const int b = row >> 12;
    float q = RATIO * (expf(PD[row * Mn + t] - diag[row] - mxq[row]) + KEPS);
    float s = blockReduceSum(q * KSUM[b * Mn + t]);
    if (t == 0) dinv[row] = 1.0f / s;
}

// ---------- 6. out = (Q @ ctx) * d_inv, replicated to 8 heads ----------
__global__ __launch_bounds__(256) void k_out(const float* __restrict__ PD,
                                             const float* __restrict__ CTX,
                                             const float* __restrict__ diag,
                                             const float* __restrict__ mxq,
                                             const float* __restrict__ dinv,
                                             float* __restrict__ OUT) {
    __shared__ float Qs[16][68];   // [m][row]
    __shared__ float Cs[16][68];   // [m][d]
    const int r0 = blockIdx.x * 64, d0 = blockIdx.y * 64;
    const int b = r0 >> 12;
    const int t = threadIdx.x, tx = t & 15, ty = t >> 4;
    const int lr = t >> 2, lc = (t & 3) * 4;    // A loader: 64 rows x 4 col-groups
    const int mr = t >> 4, c4 = (t & 15) * 4;   // B loader: 16 m-rows x 16 col-groups
    float acc[4][4] = {};
    for (int kt = 0; kt < Mn; kt += 16) {
        const int arow = r0 + lr;
        float4 p4 = *(const float4*)&PD[arow * Mn + kt + lc];
        float dm = diag[arow] + mxq[arow];
        float4 cv = *(const float4*)&CTX[b * (Mn * Dn) + (kt + mr) * Dn + d0 + c4];
        float q0 = RATIO * (expf(p4.x - dm) + KEPS);
        float q1 = RATIO * (expf(p4.y - dm) + KEPS);
        float q2 = RATIO * (expf(p4.z - dm) + KEPS);
        float q3 = RATIO * (expf(p4.w - dm) + KEPS);
        __syncthreads();
        Qs[lc + 0][lr] = q0; Qs[lc + 1][lr] = q1; Qs[lc + 2][lr] = q2; Qs[lc + 3][lr] = q3;
        *(float4*)&Cs[mr][c4] = cv;
        __syncthreads();
        #pragma unroll
        for (int kk = 0; kk < 16; kk++) {
            float4 av = *(float4*)&Qs[kk][ty * 4];
            float4 bv = *(float4*)&Cs[kk][tx * 4];
            float ar[4] = {av.x, av.y, av.z, av.w};
            float br[4] = {bv.x, bv.y, bv.z, bv.w};
            #pragma unroll
            for (int i = 0; i < 4; i++)
                #pragma unroll
                for (int j = 0; j < 4; j++)
                    acc[i][j] += ar[i] * br[j];
        }
    }
    #pragma unroll
    for (int i = 0; i < 4; i++) {
        const int row = r0 + ty * 4 + i;
        const float dv = dinv[row];
        const int bb = row >> 12, ss = row & (Sn - 1);
        float4 o = make_float4(acc[i][0] * dv, acc[i][1] * dv, acc[i][2] * dv, acc[i][3] * dv);
        #pragma unroll
        for (int h = 0; h < Hn; h++) {
            *(float4*)&OUT[(((size_t)(bb * Hn + h) * Sn + ss) * Dn) + d0 + tx * 4] = o;
        }
    }
}

extern "C" void kernel_launch(void* const* d_in, const int* in_sizes, int n_in,
                              void* d_out, int out_size, void* d_ws, size_t ws_size,
                              hipStream_t stream) {
    const float* X     = (const float*)d_in[0];
    const float* gamma = (const float*)d_in[1];
    const float* beta  = (const float*)d_in[2];
    const float* P     = (const float*)d_in[3];
    float* OUT = (float*)d_out;

    float* ws = (float*)d_ws;
    // workspace layout (floats)
    float* XN   = ws;                       // 4,194,304
    float* PD   = XN + (size_t)BSn * Dn;    // 4,194,304
    float* diag = PD + (size_t)BSn * Mn;    // 16,384
    float* mxq  = diag + BSn;               // 16,384
    float* mxk  = mxq + BSn;                // 64 (4 used)
    float* KSUM = mxk + 64;                 // 1,024
    float* CTX  = KSUM + Bn * Mn;           // 262,144
    float* dinv = CTX + Bn * Mn * Dn;       // 16,384

    hipMemsetAsync(CTX, 0, (size_t)Bn * Mn * Dn * sizeof(float), stream);
    hipMemsetAsync(KSUM, 0, (size_t)Bn * Mn * sizeof(float), stream);

    k_ln<<<BSn, 256, 0, stream>>>(X, gamma, beta, XN, diag);
    k_gemm_pd<<<dim3(BSn / 64, Mn / 64), 256, 0, stream>>>(XN, P, PD);
    k_rowmax<<<BSn, 256, 0, stream>>>(PD, mxq);
    k_batchmax<<<Bn, 256, 0, stream>>>(mxq, mxk);
    k_ctx<<<dim3(8, 16, Bn), 256, 0, stream>>>(PD, XN, diag, mxk, CTX, KSUM);
    k_dinv<<<BSn, 256, 0, stream>>>(PD, diag, mxq, KSUM, dinv);
    k_out<<<dim3(BSn / 64, Dn / 64), 256, 0, stream>>>(PD, CTX, diag, mxq, dinv, OUT);
}

// Round 2
// 262.354 us; speedup vs baseline: 1.2359x; 1.2359x over previous
//
#include <hip/hip_runtime.h>
#include <math.h>

// Problem constants (fixed by setup_inputs)
#define Bn 4
#define Hn 8
#define Sn 4096
#define Dn 256
#define Mn 256
#define BSn (Bn*Sn)          // 16384 rows
#define LN_EPS 1e-5f
#define KEPS 1e-4f
#define DATA_NORM 0.25f      // 256^-0.25
#define RATIO 0.0625f        // 256^-0.5

typedef short s8v __attribute__((ext_vector_type(8)));   // 8 bf16 (4 VGPRs)
typedef float f4v __attribute__((ext_vector_type(4)));   // MFMA acc

#define LSTR 40   // LDS row stride in bf16 elems (BK=32 + 8 pad -> 2-way-free banks)

// ---------- bf16 split helpers (manual RNE, no hip_bf16 dependency) ----------
__device__ __forceinline__ unsigned short f2bf(float x) {
    unsigned u = __float_as_uint(x);
    u += 0x7FFFu + ((u >> 16) & 1u);
    return (unsigned short)(u >> 16);
}
__device__ __forceinline__ float bf2f(unsigned short h) {
    return __uint_as_float(((unsigned)h) << 16);
}
// monotone float<->uint encoding for atomicMax-based rowmax
__device__ __forceinline__ unsigned enc_f(float f) {
    unsigned u = __float_as_uint(f);
    return (u & 0x80000000u) ? ~u : (u | 0x80000000u);
}
__device__ __forceinline__ float dec_f(unsigned u) {
    unsigned b = (u & 0x80000000u) ? (u ^ 0x80000000u) : ~u;
    return __uint_as_float(b);
}

// ---------- block reductions ----------
__device__ __forceinline__ float blockReduceSum(float v) {
    __shared__ float buf[4];
    #pragma unroll
    for (int o = 32; o > 0; o >>= 1) v += __shfl_down(v, o);
    __syncthreads();
    if ((threadIdx.x & 63) == 0) buf[threadIdx.x >> 6] = v;
    __syncthreads();
    return buf[0] + buf[1] + buf[2] + buf[3];
}
__device__ __forceinline__ float blockReduceMax(float v) {
    __shared__ float buf[4];
    #pragma unroll
    for (int o = 32; o > 0; o >>= 1) v = fmaxf(v, __shfl_down(v, o));
    __syncthreads();
    if ((threadIdx.x & 63) == 0) buf[threadIdx.x >> 6] = v;
    __syncthreads();
    return fmaxf(fmaxf(buf[0], buf[1]), fmaxf(buf[2], buf[3]));
}

// ---------- split-precision MFMA micro-kernel ----------
// 128x128 tile, BK=32, 4 waves in 2x2, each wave 64x64 = 4x4 frags of 16x16x32.
// 3 MFMAs per frag-pair: AhBh + AhBl + AlBh (drops lo*lo ~ 2^-18 rel).
__device__ __forceinline__ void split8(const float* p, unsigned short* Lh,
                                       unsigned short* Ll, int off) {
    float v[8];
    *(float4*)&v[0] = *(const float4*)p;
    *(float4*)&v[4] = *(const float4*)(p + 4);
    s8v hh, ll;
    #pragma unroll
    for (int e = 0; e < 8; e++) {
        unsigned short h = f2bf(v[e]);
        hh[e] = (short)h;
        ll[e] = (short)f2bf(v[e] - bf2f(h));
    }
    *(s8v*)&Lh[off] = hh;
    *(s8v*)&Ll[off] = ll;
}

__device__ __forceinline__ void stage_tile(const float* base, int ld,
                                           unsigned short* Lh, unsigned short* Ll, int t) {
    const int row = t >> 1, c0 = (t & 1) * 16;
    const float* p = base + (size_t)row * ld + c0;
    split8(p,     Lh, Ll, row * LSTR + c0);
    split8(p + 8, Lh, Ll, row * LSTR + c0 + 8);
}

__device__ __forceinline__ void mfma_step(const unsigned short* Ah, const unsigned short* Al,
                                          const unsigned short* Bh, const unsigned short* Bl,
                                          int wr, int wc, int lane, f4v acc[4][4]) {
    s8v ah[4], al[4], bh[4], bl[4];
    const int quad = lane >> 4, r = lane & 15;
    #pragma unroll
    for (int i = 0; i < 4; i++) {
        const int m = wr * 64 + i * 16 + r;
        ah[i] = *(const s8v*)&Ah[m * LSTR + quad * 8];
        al[i] = *(const s8v*)&Al[m * LSTR + quad * 8];
        const int n = wc * 64 + i * 16 + r;
        bh[i] = *(const s8v*)&Bh[n * LSTR + quad * 8];
        bl[i] = *(const s8v*)&Bl[n * LSTR + quad * 8];
    }
    #pragma unroll
    for (int i = 0; i < 4; i++)
        #pragma unroll
        for (int j = 0; j < 4; j++) {
            acc[i][j] = __builtin_amdgcn_mfma_f32_16x16x32_bf16(ah[i], bh[j], acc[i][j], 0, 0, 0);
            acc[i][j] = __builtin_amdgcn_mfma_f32_16x16x32_bf16(ah[i], bl[j], acc[i][j], 0, 0, 0);
            acc[i][j] = __builtin_amdgcn_mfma_f32_16x16x32_bf16(al[i], bh[j], acc[i][j], 0, 0, 0);
        }
}

// ---------- 1. LayerNorm + diag ----------
__global__ __launch_bounds__(256) void k_ln(const float* __restrict__ X,
                                            const float* __restrict__ gamma,
                                            const float* __restrict__ beta,
                                            float* __restrict__ XN,
                                            float* __restrict__ diag) {
    const int row = blockIdx.x, t = threadIdx.x;
    float x = X[(size_t)row * Dn + t];
    float mean = blockReduceSum(x) * (1.0f / Dn);
    float v = x - mean;
    float var = blockReduceSum(v * v) * (1.0f / Dn);
    float rs = rsqrtf(var + LN_EPS);
    float xn = v * rs * gamma[t] + beta[t];
    XN[(size_t)row * Dn + t] = xn;
    float d2 = blockReduceSum(xn * xn);
    if (t == 0) diag[row] = 0.5f * 0.0625f * d2;
}

// ---------- 2. GEMM1: PD = 0.25 * XN @ P^T, fused row-max ----------
__global__ __launch_bounds__(256, 2) void k_gemm1(const float* __restrict__ XN,
                                                  const float* __restrict__ P,
                                                  float* __restrict__ PD,
                                                  unsigned* __restrict__ mxqI) {
    __shared__ unsigned short Ah[128 * LSTR], Al[128 * LSTR];
    __shared__ unsigned short Bh[128 * LSTR], Bl[128 * LSTR];
    const int t = threadIdx.x, lane = t & 63, w = t >> 6;
    const int wr = w >> 1, wc = w & 1, quad = lane >> 4, cc = lane & 15;
    const int r0 = blockIdx.x * 128, m0 = blockIdx.y * 128;
    f4v acc[4][4];
    #pragma unroll
    for (int i = 0; i < 4; i++)
        #pragma unroll
        for (int j = 0; j < 4; j++)
            #pragma unroll
            for (int r = 0; r < 4; r++) acc[i][j][r] = 0.0f;

    for (int kt = 0; kt < Dn; kt += 32) {
        __syncthreads();
        stage_tile(XN + (size_t)r0 * Dn + kt, Dn, Ah, Al, t);
        stage_tile(P + (size_t)m0 * Dn + kt, Dn, Bh, Bl, t);
        __syncthreads();
        mfma_step(Ah, Al, Bh, Bl, wr, wc, lane, acc);
    }
    float rmax[4][4];
    #pragma unroll
    for (int i = 0; i < 4; i++)
        #pragma unroll
        for (int r = 0; r < 4; r++) rmax[i][r] = -INFINITY;
    #pragma unroll
    for (int i = 0; i < 4; i++) {
        const int row = r0 + wr * 64 + i * 16 + quad * 4;
        #pragma unroll
        for (int j = 0; j < 4; j++) {
            const int col = m0 + wc * 64 + j * 16 + cc;
            #pragma unroll
            for (int r = 0; r < 4; r++) {
                float v = DATA_NORM * acc[i][j][r];
                PD[(size_t)(row + r) * Mn + col] = v;
                rmax[i][r] = fmaxf(rmax[i][r], v);
            }
        }
    }
    #pragma unroll
    for (int i = 0; i < 4; i++)
        #pragma unroll
        for (int r = 0; r < 4; r++) {
            float v = rmax[i][r];
            v = fmaxf(v, __shfl_xor(v, 1));
            v = fmaxf(v, __shfl_xor(v, 2));
            v = fmaxf(v, __shfl_xor(v, 4));
            v = fmaxf(v, __shfl_xor(v, 8));
            if (cc == 0)
                atomicMax(&mxqI[r0 + wr * 64 + i * 16 + quad * 4 + r], enc_f(v));
        }
}

// ---------- 3. batch max + decode row max ----------
__global__ __launch_bounds__(256) void k_batchmax(const unsigned* __restrict__ mxqI,
                                                  float* __restrict__ mxqF,
                                                  float* __restrict__ mxk) {
    const int b = blockIdx.x;
    float m = -INFINITY;
    for (int i = threadIdx.x; i < Sn; i += 256) {
        float f = dec_f(mxqI[b * Sn + i]);
        mxqF[b * Sn + i] = f;
        m = fmaxf(m, f);
    }
    m = blockReduceMax(m);
    if (threadIdx.x == 0) mxk[b] = m;
}

// ---------- 4. K features, transposed: KT[b][m][s] + ksum ----------
__global__ __launch_bounds__(256) void k_feat(const float* __restrict__ PD,
                                              const float* __restrict__ diag,
                                              const float* __restrict__ mxk,
                                              float* __restrict__ KT,
                                              float* __restrict__ KSUM) {
    __shared__ float T[64][65];
    const int s0 = blockIdx.x * 64, m0 = blockIdx.y * 64, b = blockIdx.z;
    const int t = threadIdx.x;
    const int sr = t >> 2, mc = (t & 3) * 16;
    const int gr = b * Sn + s0 + sr;
    const float dm = diag[gr] + mxk[b];
    const float* p = PD + (size_t)gr * Mn + m0 + mc;
    float v[16];
    *(float4*)&v[0]  = *(const float4*)&p[0];
    *(float4*)&v[4]  = *(const float4*)&p[4];
    *(float4*)&v[8]  = *(const float4*)&p[8];
    *(float4*)&v[12] = *(const float4*)&p[12];
    #pragma unroll
    for (int e = 0; e < 16; e++)
        T[mc + e][sr] = RATIO * (__expf(v[e] - dm) + KEPS);
    __syncthreads();
    const int ml = t >> 2, sc = (t & 3) * 16;
    float o[16];
    float ks = 0.0f;
    #pragma unroll
    for (int i = 0; i < 16; i++) { o[i] = T[ml][sc + i]; ks += o[i]; }
    float* q = KT + ((size_t)b * Mn + m0 + ml) * Sn + s0 + sc;
    *(float4*)&q[0]  = *(float4*)&o[0];
    *(float4*)&q[4]  = *(float4*)&o[4];
    *(float4*)&q[8]  = *(float4*)&o[8];
    *(float4*)&q[12] = *(float4*)&o[12];
    ks += __shfl_xor(ks, 1);
    ks += __shfl_xor(ks, 2);
    if ((t & 3) == 0) atomicAdd(&KSUM[b * Mn + m0 + ml], ks);
}

// ---------- 5. V transpose: VT[b][d][s] ----------
__global__ __launch_bounds__(256) void k_vt(const float* __restrict__ XN,
                                            float* __restrict__ VT) {
    __shared__ float T[64][65];
    const int s0 = blockIdx.x * 64, d0 = blockIdx.y * 64, b = blockIdx.z;
    const int t = threadIdx.x;
    const int sr = t >> 2, dc = (t & 3) * 16;
    const int gr = b * Sn + s0 + sr;
    const float* p = XN + (size_t)gr * Dn + d0 + dc;
    float v[16];
    *(float4*)&v[0]  = *(const float4*)&p[0];
    *(float4*)&v[4]  = *(const float4*)&p[4];
    *(float4*)&v[8]  = *(const float4*)&p[8];
    *(float4*)&v[12] = *(const float4*)&p[12];
    #pragma unroll
    for (int e = 0; e < 16; e++) T[dc + e][sr] = v[e];
    __syncthreads();
    const int dl = t >> 2, sc = (t & 3) * 16;
    float o[16];
    #pragma unroll
    for (int i = 0; i < 16; i++) o[i] = T[dl][sc + i];
    float* q = VT + ((size_t)b * Dn + d0 + dl) * Sn + s0 + sc;
    *(float4*)&q[0]  = *(float4*)&o[0];
    *(float4*)&q[4]  = *(float4*)&o[4];
    *(float4*)&q[8]  = *(float4*)&o[8];
    *(float4*)&q[12] = *(float4*)&o[12];
}

// ---------- 6. GEMM2: PART[chunk][b][d][m] = VT_chunk @ KT_chunk^T ----------
__global__ __launch_bounds__(256, 2) void k_gemm2(const float* __restrict__ VT,
                                                  const float* __restrict__ KT,
                                                  float* __restrict__ PART) {
    __shared__ unsigned short Ah[128 * LSTR], Al[128 * LSTR];
    __shared__ unsigned short Bh[128 * LSTR], Bl[128 * LSTR];
    const int t = threadIdx.x, lane = t & 63, w = t >> 6;
    const int wr = w >> 1, wc = w & 1, quad = lane >> 4, cc = lane & 15;
    const int chunk = blockIdx.x, til = blockIdx.y, b = blockIdx.z;
    const int d0 = (til >> 1) * 128, m0 = (til & 1) * 128;
    const float* Ab = VT + ((size_t)b * Dn + d0) * Sn + chunk * 256;
    const float* Bb = KT + ((size_t)b * Mn + m0) * Sn + chunk * 256;
    f4v acc[4][4];
    #pragma unroll
    for (int i = 0; i < 4; i++)
        #pragma unroll
        for (int j = 0; j < 4; j++)
            #pragma unroll
            for (int r = 0; r < 4; r++) acc[i][j][r] = 0.0f;

    for (int kt = 0; kt < 256; kt += 32) {
        __syncthreads();
        stage_tile(Ab + kt, Sn, Ah, Al, t);
        stage_tile(Bb + kt, Sn, Bh, Bl, t);
        __syncthreads();
        mfma_step(Ah, Al, Bh, Bl, wr, wc, lane, acc);
    }
    float* dst = PART + (size_t)(chunk * Bn + b) * (Dn * Mn);
    #pragma unroll
    for (int i = 0; i < 4; i++) {
        const int drow = d0 + wr * 64 + i * 16 + quad * 4;
        #pragma unroll
        for (int j = 0; j < 4; j++) {
            const int col = m0 + wc * 64 + j * 16 + cc;
            #pragma unroll
            for (int r = 0; r < 4; r++)
                dst[(size_t)(drow + r) * Mn + col] = acc[i][j][r];
        }
    }
}

// ---------- 7. reduce 16 split-K partials -> CT[b][d][m] ----------
__global__ __launch_bounds__(256) void k_ctxred(const float* __restrict__ PART,
                                                float* __restrict__ CT) {
    const int g = blockIdx.x * 256 + threadIdx.x;   // 65536 float4 groups
    float4 s = make_float4(0.f, 0.f, 0.f, 0.f);
    #pragma unroll
    for (int c = 0; c < 16; c++) {
        float4 p = ((const float4*)PART)[(size_t)c * 65536 + g];
        s.x += p.x; s.y += p.y; s.z += p.z; s.w += p.w;
    }
    ((float4*)CT)[g] = s;
}

// ---------- 8. GEMM3: out = (Q @ CT^T) * dinv, q recomputed in staging, ----------
// ----------    dinv accumulated during staging, 8-head replicated write ----------
__global__ __launch_bounds__(256, 2) void k_gemm3(const float* __restrict__ PD,
                                                  const float* __restrict__ CT,
                                                  const float* __restrict__ diag,
                                                  const float* __restrict__ mxqF,
                                                  const float* __restrict__ KSUM,
                                                  float* __restrict__ OUT) {
    __shared__ unsigned short Ah[128 * LSTR], Al[128 * LSTR];
    __shared__ unsigned short Bh[128 * LSTR], Bl[128 * LSTR];
    __shared__ float kslds[Mn];
    __shared__ float dinvS[128];
    const int t = threadIdx.x, lane = t & 63, w = t >> 6;
    const int wr = w >> 1, wc = w & 1, quad = lane >> 4, cc = lane & 15;
    const int r0 = blockIdx.x * 128, d0 = blockIdx.y * 128;
    const int b = r0 >> 12;
    kslds[t] = KSUM[b * Mn + t];
    const int arow = t >> 1, ac0 = (t & 1) * 16;
    const int gr = r0 + arow;
    const float dm = diag[gr] + mxqF[gr];
    const float* Ab = PD + (size_t)gr * Mn + ac0;
    const float* Bb = CT + ((size_t)b * Dn + d0) * Mn;
    float qks = 0.0f;
    f4v acc[4][4];
    #pragma unroll
    for (int i = 0; i < 4; i++)
        #pragma unroll
        for (int j = 0; j < 4; j++)
            #pragma unroll
            for (int r = 0; r < 4; r++) acc[i][j][r] = 0.0f;

    for (int kt = 0; kt < Mn; kt += 32) {
        __syncthreads();   // also covers kslds on first iteration
        {   // A-stage with q transform + dinv accumulation
            const float* p = Ab + kt;
            float v[16];
            *(float4*)&v[0]  = *(const float4*)&p[0];
            *(float4*)&v[4]  = *(const float4*)&p[4];
            *(float4*)&v[8]  = *(const float4*)&p[8];
            *(float4*)&v[12] = *(const float4*)&p[12];
            #pragma unroll
            for (int e = 0; e < 16; e++) {
                float qv = RATIO * (__expf(v[e] - dm) + KEPS);
                qks += qv * kslds[kt + ac0 + e];
                v[e] = qv;
            }
            s8v hh, ll;
            #pragma unroll
            for (int half = 0; half < 2; half++) {
                #pragma unroll
                for (int e = 0; e < 8; e++) {
                    unsigned short h = f2bf(v[half * 8 + e]);
                    hh[e] = (short)h;
                    ll[e] = (short)f2bf(v[half * 8 + e] - bf2f(h));
                }
                *(s8v*)&Ah[arow * LSTR + ac0 + half * 8] = hh;
                *(s8v*)&Al[arow * LSTR + ac0 + half * 8] = ll;
            }
        }
        stage_tile(Bb + kt, Mn, Bh, Bl, t);
        __syncthreads();
        mfma_step(Ah, Al, Bh, Bl, wr, wc, lane, acc);
    }
    qks += __shfl_xor(qks, 1);
    if ((t & 1) == 0) dinvS[arow] = 1.0f / qks;
    __syncthreads();
    #pragma unroll
    for (int i = 0; i < 4; i++) {
        const int rl0 = wr * 64 + i * 16 + quad * 4;
        #pragma unroll
        for (int r = 0; r < 4; r++) {
            const int rl = rl0 + r;
            const int gr2 = r0 + rl;
            const float dv = dinvS[rl];
            const int ss = gr2 & (Sn - 1);
            const size_t base = ((size_t)(b * Hn) * Sn + ss) * Dn;
            #pragma unroll
            for (int j = 0; j < 4; j++) {
                const int col = d0 + wc * 64 + j * 16 + cc;
                const float val = acc[i][j][r] * dv;
                #pragma unroll
                for (int h = 0; h < Hn; h++)
                    OUT[base + (size_t)h * Sn * Dn + col] = val;
            }
        }
    }
}

extern "C" void kernel_launch(void* const* d_in, const int* in_sizes, int n_in,
                              void* d_out, int out_size, void* d_ws, size_t ws_size,
                              hipStream_t stream) {
    const float* X     = (const float*)d_in[0];
    const float* gamma = (const float*)d_in[1];
    const float* beta  = (const float*)d_in[2];
    const float* P     = (const float*)d_in[3];
    float* OUT = (float*)d_out;

    float* ws = (float*)d_ws;
    float* XN   = ws;                          // 4,194,304 floats (aliased as PART later)
    float* PD   = XN + (size_t)4194304;        // 4,194,304
    float* KT   = PD + (size_t)4194304;        // 4,194,304
    float* VT   = KT + (size_t)4194304;        // 4,194,304
    float* CT   = VT + (size_t)4194304;        // 262,144
    float* diag = CT + (size_t)262144;         // 16,384
    unsigned* mxqI = (unsigned*)(diag + 16384);// 16,384
    float* mxqF = (float*)(mxqI + 16384);      // 16,384
    float* mxk  = mxqF + 16384;                // 64
    float* KSUM = mxk + 64;                    // 1,024
    float* PART = XN;                          // alias: XN dead after k_vt

    hipMemsetAsync(mxqI, 0, (size_t)BSn * 4, stream);
    hipMemsetAsync(KSUM, 0, (size_t)Bn * Mn * 4, stream);

    k_ln<<<BSn, 256, 0, stream>>>(X, gamma, beta, XN, diag);
    k_gemm1<<<dim3(BSn / 128, Mn / 128), 256, 0, stream>>>(XN, P, PD, mxqI);
    k_batchmax<<<Bn, 256, 0, stream>>>(mxqI, mxqF, mxk);
    k_feat<<<dim3(Sn / 64, Mn / 64, Bn), 256, 0, stream>>>(PD, diag, mxk, KT, KSUM);
    k_vt<<<dim3(Sn / 64, Dn / 64, Bn), 256, 0, stream>>>(XN, VT);
    k_gemm2<<<dim3(16, 4, Bn), 256, 0, stream>>>(VT, KT, PART);
    k_ctxred<<<256, 256, 0, stream>>>(PART, CT);
    k_gemm3<<<dim3(BSn / 128, Dn / 128), 256, 0, stream>>>(PD, CT, diag, mxqF, KSUM, OUT);
}

// Round 3
// 221.567 us; speedup vs baseline: 1.4634x; 1.1841x over previous
//
#include <hip/hip_runtime.h>
#include <math.h>

// Problem constants (fixed by setup_inputs)
#define Bn 4
#define Hn 8
#define Sn 4096
#define Dn 256
#define Mn 256
#define BSn (Bn*Sn)          // 16384 rows
#define LN_EPS 1e-5f
#define KEPS 1e-4f
#define DATA_NORM 0.25f      // 256^-0.25
#define RATIO 0.0625f        // 256^-0.5

typedef short s8v __attribute__((ext_vector_type(8)));   // 8 bf16 (4 VGPRs)
typedef short s4v __attribute__((ext_vector_type(4)));
typedef float f4v __attribute__((ext_vector_type(4)));   // MFMA acc

#define LSTR 40   // GEMM1 (split fp32) LDS row stride, shorts
#define BSTR 72   // bf16 BK=64 LDS row stride, shorts (144B rows: uniform-8 write, 2-way read)

// ---------- bf16 helpers (manual RNE) ----------
__device__ __forceinline__ unsigned short f2bf(float x) {
    unsigned u = __float_as_uint(x);
    u += 0x7FFFu + ((u >> 16) & 1u);
    return (unsigned short)(u >> 16);
}
__device__ __forceinline__ float bf2f(unsigned short h) {
    return __uint_as_float(((unsigned)h) << 16);
}
// monotone float<->uint encoding for atomicMax rowmax (0 acts as -inf sentinel)
__device__ __forceinline__ unsigned enc_f(float f) {
    unsigned u = __float_as_uint(f);
    return (u & 0x80000000u) ? ~u : (u | 0x80000000u);
}
__device__ __forceinline__ float dec_f(unsigned u) {
    unsigned b = (u & 0x80000000u) ? (u ^ 0x80000000u) : ~u;
    return __uint_as_float(b);
}

__device__ __forceinline__ float blockReduceMax(float v) {
    __shared__ float buf[4];
    #pragma unroll
    for (int o = 32; o > 0; o >>= 1) v = fmaxf(v, __shfl_down(v, o));
    __syncthreads();
    if ((threadIdx.x & 63) == 0) buf[threadIdx.x >> 6] = v;
    __syncthreads();
    return fmaxf(fmaxf(buf[0], buf[1]), fmaxf(buf[2], buf[3]));
}

// ---------- split-precision (hi/lo bf16) micro-kernel for GEMM1 ----------
__device__ __forceinline__ void split8(const float* p, unsigned short* Lh,
                                       unsigned short* Ll, int off) {
    float v[8];
    *(float4*)&v[0] = *(const float4*)p;
    *(float4*)&v[4] = *(const float4*)(p + 4);
    s8v hh, ll;
    #pragma unroll
    for (int e = 0; e < 8; e++) {
        unsigned short h = f2bf(v[e]);
        hh[e] = (short)h;
        ll[e] = (short)f2bf(v[e] - bf2f(h));
    }
    *(s8v*)&Lh[off] = hh;
    *(s8v*)&Ll[off] = ll;
}

__device__ __forceinline__ void stage_tile(const float* base, int ld,
                                           unsigned short* Lh, unsigned short* Ll, int t) {
    const int row = t >> 1, c0 = (t & 1) * 16;
    const float* p = base + (size_t)row * ld + c0;
    split8(p,     Lh, Ll, row * LSTR + c0);
    split8(p + 8, Lh, Ll, row * LSTR + c0 + 8);
}

__device__ __forceinline__ void mfma_step(const unsigned short* Ah, const unsigned short* Al,
                                          const unsigned short* Bh, const unsigned short* Bl,
                                          int wr, int wc, int lane, f4v acc[4][4]) {
    s8v ah[4], al[4], bh[4], bl[4];
    const int quad = lane >> 4, r = lane & 15;
    #pragma unroll
    for (int i = 0; i < 4; i++) {
        const int m = wr * 64 + i * 16 + r;
        ah[i] = *(const s8v*)&Ah[m * LSTR + quad * 8];
        al[i] = *(const s8v*)&Al[m * LSTR + quad * 8];
        const int n = wc * 64 + i * 16 + r;
        bh[i] = *(const s8v*)&Bh[n * LSTR + quad * 8];
        bl[i] = *(const s8v*)&Bl[n * LSTR + quad * 8];
    }
    #pragma unroll
    for (int i = 0; i < 4; i++)
        #pragma unroll
        for (int j = 0; j < 4; j++) {
            acc[i][j] = __builtin_amdgcn_mfma_f32_16x16x32_bf16(ah[i], bh[j], acc[i][j], 0, 0, 0);
            acc[i][j] = __builtin_amdgcn_mfma_f32_16x16x32_bf16(ah[i], bl[j], acc[i][j], 0, 0, 0);
            acc[i][j] = __builtin_amdgcn_mfma_f32_16x16x32_bf16(al[i], bh[j], acc[i][j], 0, 0, 0);
        }
}

// ---------- pure-bf16 BK=64 micro-kernel for GEMM2/3 ----------
__device__ __forceinline__ void stage_bf16(const unsigned short* base, int ld,
                                           unsigned short* L, int t) {
    const int row = t >> 1, c0 = (t & 1) * 32;
    const unsigned short* p = base + (size_t)row * ld + c0;
    #pragma unroll
    for (int q = 0; q < 4; q++)
        *(s8v*)&L[row * BSTR + c0 + q * 8] = *(const s8v*)&p[q * 8];
}

__device__ __forceinline__ void mfma_step64(const unsigned short* A, const unsigned short* B,
                                            int wr, int wc, int lane, f4v acc[4][4]) {
    const int quad = lane >> 4, r = lane & 15;
    #pragma unroll
    for (int ks = 0; ks < 2; ks++) {
        s8v a[4], b[4];
        #pragma unroll
        for (int i = 0; i < 4; i++) {
            a[i] = *(const s8v*)&A[(wr * 64 + i * 16 + r) * BSTR + ks * 32 + quad * 8];
            b[i] = *(const s8v*)&B[(wc * 64 + i * 16 + r) * BSTR + ks * 32 + quad * 8];
        }
        #pragma unroll
        for (int i = 0; i < 4; i++)
            #pragma unroll
            for (int j = 0; j < 4; j++)
                acc[i][j] = __builtin_amdgcn_mfma_f32_16x16x32_bf16(a[i], b[j], acc[i][j], 0, 0, 0);
    }
}

// ---------- 1. LayerNorm (wave-per-row) + diag + mxqI zero-init ----------
__global__ __launch_bounds__(256) void k_ln(const float* __restrict__ X,
                                            const float* __restrict__ gamma,
                                            const float* __restrict__ beta,
                                            float* __restrict__ XN,
                                            float* __restrict__ diag,
                                            unsigned* __restrict__ mxqI) {
    const int w = threadIdx.x >> 6, l = threadIdx.x & 63;
    const int row = blockIdx.x * 4 + w;
    const float* p = X + (size_t)row * Dn + l * 4;
    float4 x = *(const float4*)p;
    float s = x.x + x.y + x.z + x.w;
    #pragma unroll
    for (int o = 32; o > 0; o >>= 1) s += __shfl_xor(s, o);
    const float mean = s * (1.0f / Dn);
    float4 v = make_float4(x.x - mean, x.y - mean, x.z - mean, x.w - mean);
    float vs = v.x * v.x + v.y * v.y + v.z * v.z + v.w * v.w;
    #pragma unroll
    for (int o = 32; o > 0; o >>= 1) vs += __shfl_xor(vs, o);
    const float rs = rsqrtf(vs * (1.0f / Dn) + LN_EPS);
    float4 g = *(const float4*)&gamma[l * 4];
    float4 bt = *(const float4*)&beta[l * 4];
    float4 xn = make_float4(v.x * rs * g.x + bt.x, v.y * rs * g.y + bt.y,
                            v.z * rs * g.z + bt.z, v.w * rs * g.w + bt.w);
    *(float4*)&XN[(size_t)row * Dn + l * 4] = xn;
    float d2 = xn.x * xn.x + xn.y * xn.y + xn.z * xn.z + xn.w * xn.w;
    #pragma unroll
    for (int o = 32; o > 0; o >>= 1) d2 += __shfl_xor(d2, o);
    if (l == 0) { diag[row] = 0.03125f * d2; mxqI[row] = 0u; }
}

// ---------- 2. GEMM1 (split fp32): PD = 0.25 * XN @ P^T + fused row-max ----------
__global__ __launch_bounds__(256, 2) void k_gemm1(const float* __restrict__ XN,
                                                  const float* __restrict__ P,
                                                  float* __restrict__ PD,
                                                  unsigned* __restrict__ mxqI) {
    __shared__ unsigned short Ah[128 * LSTR], Al[128 * LSTR];
    __shared__ unsigned short Bh[128 * LSTR], Bl[128 * LSTR];
    const int t = threadIdx.x, lane = t & 63, w = t >> 6;
    const int wr = w >> 1, wc = w & 1, quad = lane >> 4, cc = lane & 15;
    const int r0 = blockIdx.x * 128, m0 = blockIdx.y * 128;
    f4v acc[4][4];
    #pragma unroll
    for (int i = 0; i < 4; i++)
        #pragma unroll
        for (int j = 0; j < 4; j++)
            #pragma unroll
            for (int r = 0; r < 4; r++) acc[i][j][r] = 0.0f;

    for (int kt = 0; kt < Dn; kt += 32) {
        __syncthreads();
        stage_tile(XN + (size_t)r0 * Dn + kt, Dn, Ah, Al, t);
        stage_tile(P + (size_t)m0 * Dn + kt, Dn, Bh, Bl, t);
        __syncthreads();
        mfma_step(Ah, Al, Bh, Bl, wr, wc, lane, acc);
    }
    float rmax[4][4];
    #pragma unroll
    for (int i = 0; i < 4; i++)
        #pragma unroll
        for (int r = 0; r < 4; r++) rmax[i][r] = -INFINITY;
    #pragma unroll
    for (int i = 0; i < 4; i++) {
        const int row = r0 + wr * 64 + i * 16 + quad * 4;
        #pragma unroll
        for (int j = 0; j < 4; j++) {
            const int col = m0 + wc * 64 + j * 16 + cc;
            #pragma unroll
            for (int r = 0; r < 4; r++) {
                float v = DATA_NORM * acc[i][j][r];
                PD[(size_t)(row + r) * Mn + col] = v;
                rmax[i][r] = fmaxf(rmax[i][r], v);
            }
        }
    }
    #pragma unroll
    for (int i = 0; i < 4; i++)
        #pragma unroll
        for (int r = 0; r < 4; r++) {
            float v = rmax[i][r];
            v = fmaxf(v, __shfl_xor(v, 1));
            v = fmaxf(v, __shfl_xor(v, 2));
            v = fmaxf(v, __shfl_xor(v, 4));
            v = fmaxf(v, __shfl_xor(v, 8));
            if (cc == 0)
                atomicMax(&mxqI[r0 + wr * 64 + i * 16 + quad * 4 + r], enc_f(v));
        }
}

// ---------- 3. batch max + decode row max + KSUM zero ----------
__global__ __launch_bounds__(256) void k_batchmax(const unsigned* __restrict__ mxqI,
                                                  float* __restrict__ mxqF,
                                                  float* __restrict__ mxk,
                                                  float* __restrict__ KSUM) {
    const int b = blockIdx.x;
    KSUM[b * Mn + threadIdx.x] = 0.0f;
    float m = -INFINITY;
    for (int i = threadIdx.x; i < Sn; i += 256) {
        float f = dec_f(mxqI[b * Sn + i]);
        mxqF[b * Sn + i] = f;
        m = fmaxf(m, f);
    }
    m = blockReduceMax(m);
    if (threadIdx.x == 0) mxk[b] = m;
}

// ---------- 4. fused transposes: z<4 -> K-features (bf16 KT + ksum); z>=4 -> VT bf16 ----------
__global__ __launch_bounds__(256) void k_featvt(const float* __restrict__ PD,
                                                const float* __restrict__ XN,
                                                const float* __restrict__ diag,
                                                const float* __restrict__ mxk,
                                                unsigned short* __restrict__ KT,
                                                unsigned short* __restrict__ VT,
                                                float* __restrict__ KSUM) {
    __shared__ float T[64][65];
    const int s0 = blockIdx.x * 64, c0 = blockIdx.y * 64;
    const int z = blockIdx.z;
    const int t = threadIdx.x;
    const int sr = t >> 2, cc = (t & 3) * 16;
    if (z < 4) {
        const int b = z;
        const int gr = b * Sn + s0 + sr;
        const float dmv = diag[gr] + mxk[b];
        const float* p = PD + (size_t)gr * Mn + c0 + cc;
        float v[16];
        *(float4*)&v[0]  = *(const float4*)&p[0];
        *(float4*)&v[4]  = *(const float4*)&p[4];
        *(float4*)&v[8]  = *(const float4*)&p[8];
        *(float4*)&v[12] = *(const float4*)&p[12];
        #pragma unroll
        for (int e = 0; e < 16; e++)
            T[cc + e][sr] = RATIO * (__expf(v[e] - dmv) + KEPS);
        __syncthreads();
        const int ml = t >> 2, sc = (t & 3) * 16;
        float ks = 0.0f;
        s8v o0, o1;
        #pragma unroll
        for (int i = 0; i < 8; i++) {
            float f0 = T[ml][sc + i], f1 = T[ml][sc + 8 + i];
            ks += f0 + f1;
            o0[i] = (short)f2bf(f0);
            o1[i] = (short)f2bf(f1);
        }
        unsigned short* q = KT + ((size_t)b * Mn + c0 + ml) * Sn + s0 + sc;
        *(s8v*)&q[0] = o0;
        *(s8v*)&q[8] = o1;
        ks += __shfl_xor(ks, 1);
        ks += __shfl_xor(ks, 2);
        if ((t & 3) == 0) atomicAdd(&KSUM[b * Mn + c0 + ml], ks);
    } else {
        const int b = z - 4;
        const int gr = b * Sn + s0 + sr;
        const float* p = XN + (size_t)gr * Dn + c0 + cc;
        float v[16];
        *(float4*)&v[0]  = *(const float4*)&p[0];
        *(float4*)&v[4]  = *(const float4*)&p[4];
        *(float4*)&v[8]  = *(const float4*)&p[8];
        *(float4*)&v[12] = *(const float4*)&p[12];
        #pragma unroll
        for (int e = 0; e < 16; e++) T[cc + e][sr] = v[e];
        __syncthreads();
        const int dl = t >> 2, sc = (t & 3) * 16;
        s8v o0, o1;
        #pragma unroll
        for (int i = 0; i < 8; i++) {
            o0[i] = (short)f2bf(T[dl][sc + i]);
            o1[i] = (short)f2bf(T[dl][sc + 8 + i]);
        }
        unsigned short* q = VT + ((size_t)b * Dn + c0 + dl) * Sn + s0 + sc;
        *(s8v*)&q[0] = o0;
        *(s8v*)&q[8] = o1;
    }
}

// ---------- 5. GEMM2 (bf16): PART[chunk][b][d][m] = VT_chunk @ KT_chunk^T ----------
__global__ __launch_bounds__(256, 2) void k_gemm2(const unsigned short* __restrict__ VT,
                                                  const unsigned short* __restrict__ KT,
                                                  float* __restrict__ PART) {
    __shared__ unsigned short Abuf[128 * BSTR], Bbuf[128 * BSTR];
    const int t = threadIdx.x, lane = t & 63, w = t >> 6;
    const int wr = w >> 1, wc = w & 1, quad = lane >> 4, cc = lane & 15;
    const int chunk = blockIdx.x, til = blockIdx.y, b = blockIdx.z;
    const int d0 = (til >> 1) * 128, m0 = (til & 1) * 128;
    const unsigned short* Ab = VT + ((size_t)b * Dn + d0) * Sn + chunk * 256;
    const unsigned short* Bb = KT + ((size_t)b * Mn + m0) * Sn + chunk * 256;
    f4v acc[4][4];
    #pragma unroll
    for (int i = 0; i < 4; i++)
        #pragma unroll
        for (int j = 0; j < 4; j++)
            #pragma unroll
            for (int r = 0; r < 4; r++) acc[i][j][r] = 0.0f;

    for (int kt = 0; kt < 256; kt += 64) {
        __syncthreads();
        stage_bf16(Ab + kt, Sn, Abuf, t);
        stage_bf16(Bb + kt, Sn, Bbuf, t);
        __syncthreads();
        mfma_step64(Abuf, Bbuf, wr, wc, lane, acc);
    }
    float* dst = PART + (size_t)(chunk * Bn + b) * (Dn * Mn);
    #pragma unroll
    for (int i = 0; i < 4; i++) {
        const int drow = d0 + wr * 64 + i * 16 + quad * 4;
        #pragma unroll
        for (int j = 0; j < 4; j++) {
            const int col = m0 + wc * 64 + j * 16 + cc;
            #pragma unroll
            for (int r = 0; r < 4; r++)
                dst[(size_t)(drow + r) * Mn + col] = acc[i][j][r];
        }
    }
}

// ---------- 6. reduce 16 split-K partials -> CT bf16 [b][d][m] ----------
__global__ __launch_bounds__(256) void k_ctxred(const float* __restrict__ PART,
                                                unsigned short* __restrict__ CT) {
    const int g = blockIdx.x * 256 + threadIdx.x;   // 65536 float4 groups
    float4 s = make_float4(0.f, 0.f, 0.f, 0.f);
    #pragma unroll
    for (int c = 0; c < 16; c++) {
        float4 p = *(const float4*)&PART[(size_t)c * 262144 + (size_t)g * 4];
        s.x += p.x; s.y += p.y; s.z += p.z; s.w += p.w;
    }
    s4v o;
    o[0] = (short)f2bf(s.x); o[1] = (short)f2bf(s.y);
    o[2] = (short)f2bf(s.z); o[3] = (short)f2bf(s.w);
    *(s4v*)&CT[(size_t)g * 4] = o;
}

// ---------- 7. GEMM3 (bf16): out = (Q @ CT^T) * dinv, q + dinv fused, 8-head write ----------
__global__ __launch_bounds__(256, 2) void k_gemm3(const float* __restrict__ PD,
                                                  const unsigned short* __restrict__ CT,
                                                  const float* __restrict__ diag,
                                                  const float* __restrict__ mxqF,
                                                  const float* __restrict__ KSUM,
                                                  float* __restrict__ OUT) {
    __shared__ unsigned short Abuf[128 * BSTR], Bbuf[128 * BSTR];
    __shared__ float kslds[Mn];
    __shared__ float dinvS[128];
    const int t = threadIdx.x, lane = t & 63, w = t >> 6;
    const int wr = w >> 1, wc = w & 1, quad = lane >> 4, cc = lane & 15;
    const int r0 = blockIdx.x * 128, d0 = blockIdx.y * 128;
    const int b = r0 >> 12;
    kslds[t] = KSUM[b * Mn + t];
    const int arow = t >> 1, h = t & 1;
    const int gr = r0 + arow;
    const float dm = diag[gr] + mxqF[gr];
    const float* Ap = PD + (size_t)gr * Mn + h * 32;
    const unsigned short* Bb = CT + ((size_t)b * Dn + d0) * Mn;
    float qks = 0.0f;
    f4v acc[4][4];
    #pragma unroll
    for (int i = 0; i < 4; i++)
        #pragma unroll
        for (int j = 0; j < 4; j++)
            #pragma unroll
            for (int r = 0; r < 4; r++) acc[i][j][r] = 0.0f;

    for (int kt = 0; kt < Mn; kt += 64) {
        __syncthreads();   // also covers kslds on first iteration
        {   // A-stage: q features + dinv accumulation
            float v[32];
            #pragma unroll
            for (int q4 = 0; q4 < 8; q4++)
                *(float4*)&v[q4 * 4] = *(const float4*)&Ap[kt + q4 * 4];
            #pragma unroll
            for (int e = 0; e < 32; e++) {
                float qv = RATIO * (__expf(v[e] - dm) + KEPS);
                qks += qv * kslds[kt + h * 32 + e];
                v[e] = qv;
            }
            #pragma unroll
            for (int g8 = 0; g8 < 4; g8++) {
                s8v hh;
                #pragma unroll
                for (int e = 0; e < 8; e++) hh[e] = (short)f2bf(v[g8 * 8 + e]);
                *(s8v*)&Abuf[arow * BSTR + h * 32 + g8 * 8] = hh;
            }
        }
        stage_bf16(Bb + kt, Mn, Bbuf, t);
        __syncthreads();
        mfma_step64(Abuf, Bbuf, wr, wc, lane, acc);
    }
    qks += __shfl_xor(qks, 1);
    if (h == 0) dinvS[arow] = 1.0f / qks;
    __syncthreads();
    #pragma unroll
    for (int i = 0; i < 4; i++) {
        const int rl0 = wr * 64 + i * 16 + quad * 4;
        #pragma unroll
        for (int r = 0; r < 4; r++) {
            const int rl = rl0 + r;
            const int gr2 = r0 + rl;
            const float dv = dinvS[rl];
            const int ss = gr2 & (Sn - 1);
            const size_t base = ((size_t)(b * Hn) * Sn + ss) * Dn;
            #pragma unroll
            for (int j = 0; j < 4; j++) {
                const int col = d0 + wc * 64 + j * 16 + cc;
                const float val = acc[i][j][r] * dv;
                #pragma unroll
                for (int hh = 0; hh < Hn; hh++)
                    OUT[base + (size_t)hh * Sn * Dn + col] = val;
            }
        }
    }
}

extern "C" void kernel_launch(void* const* d_in, const int* in_sizes, int n_in,
                              void* d_out, int out_size, void* d_ws, size_t ws_size,
                              hipStream_t stream) {
    const float* X     = (const float*)d_in[0];
    const float* gamma = (const float*)d_in[1];
    const float* beta  = (const float*)d_in[2];
    const float* P     = (const float*)d_in[3];
    float* OUT = (float*)d_out;

    float* ws = (float*)d_ws;
    float* XN   = ws;                            // 4,194,304 f (aliased as PART later)
    float* PD   = XN + (size_t)4194304;          // 4,194,304 f
    float* diag = PD + (size_t)4194304;          // 16,384
    unsigned* mxqI = (unsigned*)(diag + 16384);  // 16,384
    float* mxqF = (float*)(mxqI + 16384);        // 16,384
    float* mxk  = mxqF + 16384;                  // 64
    float* KSUM = mxk + 64;                      // 1,024
    unsigned short* KT = (unsigned short*)(KSUM + 1024);  // 4,194,304 shorts
    unsigned short* VT = KT + (size_t)4194304;            // 4,194,304 shorts
    unsigned short* CT = VT + (size_t)4194304;            // 262,144 shorts
    float* PART = XN;   // alias: XN dead after k_featvt

    k_ln<<<BSn / 4, 256, 0, stream>>>(X, gamma, beta, XN, diag, mxqI);
    k_gemm1<<<dim3(BSn / 128, Mn / 128), 256, 0, stream>>>(XN, P, PD, mxqI);
    k_batchmax<<<Bn, 256, 0, stream>>>(mxqI, mxqF, mxk, KSUM);
    k_featvt<<<dim3(Sn / 64, 4, 8), 256, 0, stream>>>(PD, XN, diag, mxk, KT, VT, KSUM);
    k_gemm2<<<dim3(16, 4, Bn), 256, 0, stream>>>(VT, KT, PART);
    k_ctxred<<<256, 256, 0, stream>>>(PART, CT);
    k_gemm3<<<dim3(BSn / 128, Dn / 128), 256, 0, stream>>>(PD, CT, diag, mxqF, KSUM, OUT);
}

// Round 4
// 206.865 us; speedup vs baseline: 1.5674x; 1.0711x over previous
//
#include <hip/hip_runtime.h>
#include <math.h>

// Problem constants (fixed by setup_inputs)
#define Bn 4
#define Hn 8
#define Sn 4096
#define Dn 256
#define Mn 256
#define BSn (Bn*Sn)          // 16384 rows
#define LN_EPS 1e-5f
#define KEPS 1e-4f
#define DATA_NORM 0.25f      // 256^-0.25
#define RATIO 0.0625f        // 256^-0.5

typedef short s8v __attribute__((ext_vector_type(8)));   // 8 bf16 (4 VGPRs)
typedef short s4v __attribute__((ext_vector_type(4)));
typedef float f4v __attribute__((ext_vector_type(4)));   // MFMA acc

#define BSTR 72   // bf16 BK=64 LDS row stride, shorts (144 B rows -> 2-way bank aliasing, free)

// ---------- bf16 helpers (manual RNE) ----------
__device__ __forceinline__ unsigned short f2bf(float x) {
    unsigned u = __float_as_uint(x);
    u += 0x7FFFu + ((u >> 16) & 1u);
    return (unsigned short)(u >> 16);
}
__device__ __forceinline__ float bf2f(unsigned short h) {
    return __uint_as_float(((unsigned)h) << 16);
}
// monotone float<->uint encoding for atomicMax rowmax (0 acts as sentinel below all data)
__device__ __forceinline__ unsigned enc_f(float f) {
    unsigned u = __float_as_uint(f);
    return (u & 0x80000000u) ? ~u : (u | 0x80000000u);
}
__device__ __forceinline__ float dec_f(unsigned u) {
    unsigned b = (u & 0x80000000u) ? (u ^ 0x80000000u) : ~u;
    return __uint_as_float(b);
}

__device__ __forceinline__ float blockReduceMax(float v) {
    __shared__ float buf[4];
    #pragma unroll
    for (int o = 32; o > 0; o >>= 1) v = fmaxf(v, __shfl_down(v, o));
    __syncthreads();
    if ((threadIdx.x & 63) == 0) buf[threadIdx.x >> 6] = v;
    __syncthreads();
    return fmaxf(fmaxf(buf[0], buf[1]), fmaxf(buf[2], buf[3]));
}

// ---------- pure-bf16 BK=64 staging + MFMA helpers (128-row tiles, GEMM2) ----------
__device__ __forceinline__ void stage_bf16(const unsigned short* base, int ld,
                                           unsigned short* L, int t) {
    const int row = t >> 1, c0 = (t & 1) * 32;
    const unsigned short* p = base + (size_t)row * ld + c0;
    #pragma unroll
    for (int q = 0; q < 4; q++)
        *(s8v*)&L[row * BSTR + c0 + q * 8] = *(const s8v*)&p[q * 8];
}

__device__ __forceinline__ void mfma_step64(const unsigned short* A, const unsigned short* B,
                                            int wr, int wc, int lane, f4v acc[4][4]) {
    const int quad = lane >> 4, r = lane & 15;
    #pragma unroll
    for (int ks = 0; ks < 2; ks++) {
        s8v a[4], b[4];
        #pragma unroll
        for (int i = 0; i < 4; i++) {
            a[i] = *(const s8v*)&A[(wr * 64 + i * 16 + r) * BSTR + ks * 32 + quad * 8];
            b[i] = *(const s8v*)&B[(wc * 64 + i * 16 + r) * BSTR + ks * 32 + quad * 8];
        }
        #pragma unroll
        for (int i = 0; i < 4; i++)
            #pragma unroll
            for (int j = 0; j < 4; j++)
                acc[i][j] = __builtin_amdgcn_mfma_f32_16x16x32_bf16(a[i], b[j], acc[i][j], 0, 0, 0);
    }
}

// ---------- 0. split P into hi/lo bf16 (once, instead of per-block in GEMM1) ----------
__global__ __launch_bounds__(256) void k_splitp(const float* __restrict__ P,
                                                unsigned short* __restrict__ Ph,
                                                unsigned short* __restrict__ Pl) {
    const int i = (blockIdx.x * 256 + threadIdx.x) * 8;
    float v[8];
    *(float4*)&v[0] = *(const float4*)&P[i];
    *(float4*)&v[4] = *(const float4*)&P[i + 4];
    s8v hh, ll;
    #pragma unroll
    for (int e = 0; e < 8; e++) {
        unsigned short h = f2bf(v[e]);
        hh[e] = (short)h;
        ll[e] = (short)f2bf(v[e] - bf2f(h));
    }
    *(s8v*)&Ph[i] = hh;
    *(s8v*)&Pl[i] = ll;
}

// ---------- 1. LayerNorm (wave-per-row) -> split XNh/XNl + diag + mxqI zero ----------
__global__ __launch_bounds__(256) void k_ln(const float* __restrict__ X,
                                            const float* __restrict__ gamma,
                                            const float* __restrict__ beta,
                                            unsigned short* __restrict__ XNh,
                                            unsigned short* __restrict__ XNl,
                                            float* __restrict__ diag,
                                            unsigned* __restrict__ mxqI) {
    const int w = threadIdx.x >> 6, l = threadIdx.x & 63;
    const int row = blockIdx.x * 4 + w;
    float4 x = *(const float4*)&X[(size_t)row * Dn + l * 4];
    float s = x.x + x.y + x.z + x.w;
    #pragma unroll
    for (int o = 32; o > 0; o >>= 1) s += __shfl_xor(s, o);
    const float mean = s * (1.0f / Dn);
    float xn[4] = {x.x - mean, x.y - mean, x.z - mean, x.w - mean};
    float vs = xn[0] * xn[0] + xn[1] * xn[1] + xn[2] * xn[2] + xn[3] * xn[3];
    #pragma unroll
    for (int o = 32; o > 0; o >>= 1) vs += __shfl_xor(vs, o);
    const float rs = rsqrtf(vs * (1.0f / Dn) + LN_EPS);
    float4 g = *(const float4*)&gamma[l * 4];
    float4 bt = *(const float4*)&beta[l * 4];
    xn[0] = xn[0] * rs * g.x + bt.x;
    xn[1] = xn[1] * rs * g.y + bt.y;
    xn[2] = xn[2] * rs * g.z + bt.z;
    xn[3] = xn[3] * rs * g.w + bt.w;
    s4v hv, lv;
    float d2 = 0.0f;
    #pragma unroll
    for (int c = 0; c < 4; c++) {
        d2 += xn[c] * xn[c];
        unsigned short h = f2bf(xn[c]);
        hv[c] = (short)h;
        lv[c] = (short)f2bf(xn[c] - bf2f(h));
    }
    *(s4v*)&XNh[(size_t)row * Dn + l * 4] = hv;
    *(s4v*)&XNl[(size_t)row * Dn + l * 4] = lv;
    #pragma unroll
    for (int o = 32; o > 0; o >>= 1) d2 += __shfl_xor(d2, o);
    if (l == 0) { diag[row] = 0.03125f * d2; mxqI[row] = 0u; }
}

// ---------- 2. GEMM1 (split fp32, pre-split operands): PD = 0.25*XN@P^T + rowmax ----------
// 64x128 tile, BK=64, grid 512 (2 blocks/CU). Staging = pure b128 copies.
__global__ __launch_bounds__(256, 2) void k_gemm1(const unsigned short* __restrict__ XNh,
                                                  const unsigned short* __restrict__ XNl,
                                                  const unsigned short* __restrict__ Ph,
                                                  const unsigned short* __restrict__ Pl,
                                                  float* __restrict__ PD,
                                                  unsigned* __restrict__ mxqI) {
    __shared__ unsigned short Ah[64 * BSTR], Al[64 * BSTR];
    __shared__ unsigned short Bh[128 * BSTR], Bl[128 * BSTR];
    const int t = threadIdx.x, lane = t & 63, w = t >> 6;
    const int wr = w >> 1, wc = w & 1, quad = lane >> 4, cc = lane & 15;
    const int r0 = blockIdx.x * 64, m0 = blockIdx.y * 128;
    const int ar0 = t >> 3, ac8 = (t & 7) * 8;
    f4v acc[2][4];
    #pragma unroll
    for (int i = 0; i < 2; i++)
        #pragma unroll
        for (int j = 0; j < 4; j++)
            #pragma unroll
            for (int r = 0; r < 4; r++) acc[i][j][r] = 0.0f;

    for (int kt = 0; kt < Dn; kt += 64) {
        __syncthreads();
        *(s8v*)&Ah[ar0 * BSTR + ac8]        = *(const s8v*)&XNh[(size_t)(r0 + ar0) * Dn + kt + ac8];
        *(s8v*)&Al[ar0 * BSTR + ac8]        = *(const s8v*)&XNl[(size_t)(r0 + ar0) * Dn + kt + ac8];
        *(s8v*)&Ah[(ar0 + 32) * BSTR + ac8] = *(const s8v*)&XNh[(size_t)(r0 + ar0 + 32) * Dn + kt + ac8];
        *(s8v*)&Al[(ar0 + 32) * BSTR + ac8] = *(const s8v*)&XNl[(size_t)(r0 + ar0 + 32) * Dn + kt + ac8];
        #pragma unroll
        for (int ss = 0; ss < 4; ss++) {
            const int row = ar0 + ss * 32;
            *(s8v*)&Bh[row * BSTR + ac8] = *(const s8v*)&Ph[(size_t)(m0 + row) * Dn + kt + ac8];
            *(s8v*)&Bl[row * BSTR + ac8] = *(const s8v*)&Pl[(size_t)(m0 + row) * Dn + kt + ac8];
        }
        __syncthreads();
        #pragma unroll
        for (int ks = 0; ks < 2; ks++) {
            s8v ah[2], al[2], bh[4], bl[4];
            #pragma unroll
            for (int i = 0; i < 2; i++) {
                const int m = wr * 32 + i * 16 + cc;
                ah[i] = *(const s8v*)&Ah[m * BSTR + ks * 32 + quad * 8];
                al[i] = *(const s8v*)&Al[m * BSTR + ks * 32 + quad * 8];
            }
            #pragma unroll
            for (int j = 0; j < 4; j++) {
                const int n = wc * 64 + j * 16 + cc;
                bh[j] = *(const s8v*)&Bh[n * BSTR + ks * 32 + quad * 8];
                bl[j] = *(const s8v*)&Bl[n * BSTR + ks * 32 + quad * 8];
            }
            #pragma unroll
            for (int i = 0; i < 2; i++)
                #pragma unroll
                for (int j = 0; j < 4; j++) {
                    acc[i][j] = __builtin_amdgcn_mfma_f32_16x16x32_bf16(ah[i], bh[j], acc[i][j], 0, 0, 0);
                    acc[i][j] = __builtin_amdgcn_mfma_f32_16x16x32_bf16(ah[i], bl[j], acc[i][j], 0, 0, 0);
                    acc[i][j] = __builtin_amdgcn_mfma_f32_16x16x32_bf16(al[i], bh[j], acc[i][j], 0, 0, 0);
                }
        }
    }
    float rmax[2][4];
    #pragma unroll
    for (int i = 0; i < 2; i++)
        #pragma unroll
        for (int r = 0; r < 4; r++) rmax[i][r] = -INFINITY;
    #pragma unroll
    for (int i = 0; i < 2; i++) {
        const int row = r0 + wr * 32 + i * 16 + quad * 4;
        #pragma unroll
        for (int j = 0; j < 4; j++) {
            const int col = m0 + wc * 64 + j * 16 + cc;
            #pragma unroll
            for (int r = 0; r < 4; r++) {
                float v = DATA_NORM * acc[i][j][r];
                PD[(size_t)(row + r) * Mn + col] = v;
                rmax[i][r] = fmaxf(rmax[i][r], v);
            }
        }
    }
    #pragma unroll
    for (int i = 0; i < 2; i++)
        #pragma unroll
        for (int r = 0; r < 4; r++) {
            float v = rmax[i][r];
            v = fmaxf(v, __shfl_xor(v, 1));
            v = fmaxf(v, __shfl_xor(v, 2));
            v = fmaxf(v, __shfl_xor(v, 4));
            v = fmaxf(v, __shfl_xor(v, 8));
            if (cc == 0)
                atomicMax(&mxqI[r0 + wr * 32 + i * 16 + quad * 4 + r], enc_f(v));
        }
}

// ---------- 3. batch max + decode row max + KSUM zero ----------
__global__ __launch_bounds__(256) void k_batchmax(const unsigned* __restrict__ mxqI,
                                                  float* __restrict__ mxqF,
                                                  float* __restrict__ mxk,
                                                  float* __restrict__ KSUM) {
    const int b = blockIdx.x;
    KSUM[b * Mn + threadIdx.x] = 0.0f;
    float m = -INFINITY;
    for (int i = threadIdx.x; i < Sn; i += 256) {
        float f = dec_f(mxqI[b * Sn + i]);
        mxqF[b * Sn + i] = f;
        m = fmaxf(m, f);
    }
    m = blockReduceMax(m);
    if (threadIdx.x == 0) mxk[b] = m;
}

// ---------- 4. features: z<4 -> K (bf16 KT transposed + ksum) AND Q (bf16 row-major);
// ----------           z>=4 -> V transpose (bf16 VT from XNh) ----------
__global__ __launch_bounds__(256) void k_featvt(const float* __restrict__ PD,
                                                const unsigned short* __restrict__ XNh,
                                                const float* __restrict__ diag,
                                                const float* __restrict__ mxk,
                                                const float* __restrict__ mxqF,
                                                unsigned short* __restrict__ KT,
                                                unsigned short* __restrict__ QR,
                                                unsigned short* __restrict__ VT,
                                                float* __restrict__ KSUM) {
    const int s0 = blockIdx.x * 64, c0 = blockIdx.y * 64, z = blockIdx.z;
    const int t = threadIdx.x;
    const int sr = t >> 2, cc16 = (t & 3) * 16;
    if (z < 4) {
        __shared__ float T[64][65];
        const int b = z;
        const int gr = b * Sn + s0 + sr;
        const float dmv = diag[gr] + mxk[b];
        const float srow = __expf(mxk[b] - mxqF[gr]);   // exp(mxk - mxq_row) >= 1
        const float* p = PD + (size_t)gr * Mn + c0 + cc16;
        float v[16];
        *(float4*)&v[0]  = *(const float4*)&p[0];
        *(float4*)&v[4]  = *(const float4*)&p[4];
        *(float4*)&v[8]  = *(const float4*)&p[8];
        *(float4*)&v[12] = *(const float4*)&p[12];
        s8v q0, q1;
        #pragma unroll
        for (int e = 0; e < 16; e++) {
            float ev = __expf(v[e] - dmv);
            T[cc16 + e][sr] = RATIO * (ev + KEPS);                 // k feature (fp32 for KT)
            unsigned short qb = f2bf(RATIO * (ev * srow + KEPS));  // exact q feature
            if (e < 8) q0[e] = (short)qb; else q1[e - 8] = (short)qb;
        }
        *(s8v*)&QR[(size_t)gr * Mn + c0 + cc16]     = q0;
        *(s8v*)&QR[(size_t)gr * Mn + c0 + cc16 + 8] = q1;
        __syncthreads();
        const int ml = t >> 2, sc = (t & 3) * 16;
        float ks = 0.0f;
        s8v o0, o1;
        #pragma unroll
        for (int i = 0; i < 8; i++) {
            float f0 = T[ml][sc + i], f1 = T[ml][sc + 8 + i];
            ks += f0 + f1;
            o0[i] = (short)f2bf(f0);
            o1[i] = (short)f2bf(f1);
        }
        unsigned short* q = KT + ((size_t)b * Mn + c0 + ml) * Sn + s0 + sc;
        *(s8v*)&q[0] = o0;
        *(s8v*)&q[8] = o1;
        ks += __shfl_xor(ks, 1);
        ks += __shfl_xor(ks, 2);
        if ((t & 3) == 0) atomicAdd(&KSUM[b * Mn + c0 + ml], ks);
    } else {
        __shared__ unsigned short Tu[64][72];
        const int b = z - 4;
        const int gr = b * Sn + s0 + sr;
        const unsigned short* p = XNh + (size_t)gr * Dn + c0 + cc16;
        s8v x0 = *(const s8v*)&p[0], x1 = *(const s8v*)&p[8];
        #pragma unroll
        for (int e = 0; e < 8; e++) {
            Tu[cc16 + e][sr]     = (unsigned short)x0[e];
            Tu[cc16 + 8 + e][sr] = (unsigned short)x1[e];
        }
        __syncthreads();
        const int dl = t >> 2, sc = (t & 3) * 16;
        s8v o0, o1;
        #pragma unroll
        for (int i = 0; i < 8; i++) {
            o0[i] = (short)Tu[dl][sc + i];
            o1[i] = (short)Tu[dl][sc + 8 + i];
        }
        unsigned short* q = VT + ((size_t)b * Dn + c0 + dl) * Sn + s0 + sc;
        *(s8v*)&q[0] = o0;
        *(s8v*)&q[8] = o1;
    }
}

// ---------- 5. GEMM2 (bf16): PART[chunk][b][d][m] = VT_chunk @ KT_chunk^T ----------
__global__ __launch_bounds__(256, 2) void k_gemm2(const unsigned short* __restrict__ VT,
                                                  const unsigned short* __restrict__ KT,
                                                  float* __restrict__ PART) {
    __shared__ unsigned short Abuf[128 * BSTR], Bbuf[128 * BSTR];
    const int t = threadIdx.x, lane = t & 63, w = t >> 6;
    const int wr = w >> 1, wc = w & 1, quad = lane >> 4, cc = lane & 15;
    const int chunk = blockIdx.x, til = blockIdx.y, b = blockIdx.z;
    const int d0 = (til >> 1) * 128, m0 = (til & 1) * 128;
    const unsigned short* Ab = VT + ((size_t)b * Dn + d0) * Sn + chunk * 256;
    const unsigned short* Bb = KT + ((size_t)b * Mn + m0) * Sn + chunk * 256;
    f4v acc[4][4];
    #pragma unroll
    for (int i = 0; i < 4; i++)
        #pragma unroll
        for (int j = 0; j < 4; j++)
            #pragma unroll
            for (int r = 0; r < 4; r++) acc[i][j][r] = 0.0f;

    for (int kt = 0; kt < 256; kt += 64) {
        __syncthreads();
        stage_bf16(Ab + kt, Sn, Abuf, t);
        stage_bf16(Bb + kt, Sn, Bbuf, t);
        __syncthreads();
        mfma_step64(Abuf, Bbuf, wr, wc, lane, acc);
    }
    float* dst = PART + (size_t)(chunk * Bn + b) * (Dn * Mn);
    #pragma unroll
    for (int i = 0; i < 4; i++) {
        const int drow = d0 + wr * 64 + i * 16 + quad * 4;
        #pragma unroll
        for (int j = 0; j < 4; j++) {
            const int col = m0 + wc * 64 + j * 16 + cc;
            #pragma unroll
            for (int r = 0; r < 4; r++)
                dst[(size_t)(drow + r) * Mn + col] = acc[i][j][r];
        }
    }
}

// ---------- 6. reduce 16 split-K partials -> CT bf16 [b][d][m] ----------
__global__ __launch_bounds__(256) void k_ctxred(const float* __restrict__ PART,
                                                unsigned short* __restrict__ CT) {
    const int g = blockIdx.x * 256 + threadIdx.x;   // 65536 float4 groups
    float4 s = make_float4(0.f, 0.f, 0.f, 0.f);
    #pragma unroll
    for (int c = 0; c < 16; c++) {
        float4 p = *(const float4*)&PART[(size_t)c * 262144 + (size_t)g * 4];
        s.x += p.x; s.y += p.y; s.z += p.z; s.w += p.w;
    }
    s4v o;
    o[0] = (short)f2bf(s.x); o[1] = (short)f2bf(s.y);
    o[2] = (short)f2bf(s.z); o[3] = (short)f2bf(s.w);
    *(s4v*)&CT[(size_t)g * 4] = o;
}

// ---------- 7. GEMM3 (pure bf16): out = (QR @ CT^T) * dinv, qks in staging, 8-head write ----------
// 64x128 tile, BK=64, grid 512. A-staging = pure copies + fma dot with ksum.
__global__ __launch_bounds__(256, 2) void k_gemm3(const unsigned short* __restrict__ QR,
                                                  const unsigned short* __restrict__ CT,
                                                  const float* __restrict__ KSUM,
                                                  float* __restrict__ OUT) {
    __shared__ unsigned short Abuf[64 * BSTR], Bbuf[128 * BSTR];
    __shared__ float kslds[Mn];
    __shared__ float dinvS[64];
    const int t = threadIdx.x, lane = t & 63, w = t >> 6;
    const int wr = w >> 1, wc = w & 1, quad = lane >> 4, cc = lane & 15;
    const int r0 = blockIdx.x * 64, d0 = blockIdx.y * 128;
    const int b = r0 >> 12;
    kslds[t] = KSUM[b * Mn + t];
    const int ar0 = t >> 3, ac8 = (t & 7) * 8;
    float qks0 = 0.0f, qks1 = 0.0f;
    f4v acc[2][4];
    #pragma unroll
    for (int i = 0; i < 2; i++)
        #pragma unroll
        for (int j = 0; j < 4; j++)
            #pragma unroll
            for (int r = 0; r < 4; r++) acc[i][j][r] = 0.0f;

    for (int kt = 0; kt < Mn; kt += 64) {
        __syncthreads();   // covers kslds on first iteration
        s8v a0 = *(const s8v*)&QR[(size_t)(r0 + ar0) * Mn + kt + ac8];
        s8v a1 = *(const s8v*)&QR[(size_t)(r0 + ar0 + 32) * Mn + kt + ac8];
        *(s8v*)&Abuf[ar0 * BSTR + ac8]        = a0;
        *(s8v*)&Abuf[(ar0 + 32) * BSTR + ac8] = a1;
        #pragma unroll
        for (int e = 0; e < 8; e++) {
            const float ks = kslds[kt + ac8 + e];
            qks0 += bf2f((unsigned short)a0[e]) * ks;
            qks1 += bf2f((unsigned short)a1[e]) * ks;
        }
        #pragma unroll
        for (int ss = 0; ss < 4; ss++) {
            const int row = ar0 + ss * 32;
            *(s8v*)&Bbuf[row * BSTR + ac8] =
                *(const s8v*)&CT[((size_t)b * Dn + d0 + row) * Mn + kt + ac8];
        }
        __syncthreads();
        #pragma unroll
        for (int ks = 0; ks < 2; ks++) {
            s8v a[2], bb[4];
            #pragma unroll
            for (int i = 0; i < 2; i++)
                a[i] = *(const s8v*)&Abuf[(wr * 32 + i * 16 + cc) * BSTR + ks * 32 + quad * 8];
            #pragma unroll
            for (int j = 0; j < 4; j++)
                bb[j] = *(const s8v*)&Bbuf[(wc * 64 + j * 16 + cc) * BSTR + ks * 32 + quad * 8];
            #pragma unroll
            for (int i = 0; i < 2; i++)
                #pragma unroll
                for (int j = 0; j < 4; j++)
                    acc[i][j] = __builtin_amdgcn_mfma_f32_16x16x32_bf16(a[i], bb[j], acc[i][j], 0, 0, 0);
        }
    }
    qks0 += __shfl_xor(qks0, 1); qks0 += __shfl_xor(qks0, 2); qks0 += __shfl_xor(qks0, 4);
    qks1 += __shfl_xor(qks1, 1); qks1 += __shfl_xor(qks1, 2); qks1 += __shfl_xor(qks1, 4);
    if ((t & 7) == 0) {
        dinvS[ar0]      = 1.0f / qks0;
        dinvS[ar0 + 32] = 1.0f / qks1;
    }
    __syncthreads();
    #pragma unroll
    for (int i = 0; i < 2; i++) {
        const int rl0 = wr * 32 + i * 16 + quad * 4;
        #pragma unroll
        for (int r = 0; r < 4; r++) {
            const int rl = rl0 + r;
            const int gr = r0 + rl;
            const float dv = dinvS[rl];
            const int ss = gr & (Sn - 1);
            const size_t base = ((size_t)(b * Hn) * Sn + ss) * Dn;
            #pragma unroll
            for (int j = 0; j < 4; j++) {
                const int col = d0 + wc * 64 + j * 16 + cc;
                const float val = acc[i][j][r] * dv;
                #pragma unroll
                for (int h = 0; h < Hn; h++)
                    OUT[base + (size_t)h * Sn * Dn + col] = val;
            }
        }
    }
}

extern "C" void kernel_launch(void* const* d_in, const int* in_sizes, int n_in,
                              void* d_out, int out_size, void* d_ws, size_t ws_size,
                              hipStream_t stream) {
    const float* X     = (const float*)d_in[0];
    const float* gamma = (const float*)d_in[1];
    const float* beta  = (const float*)d_in[2];
    const float* P     = (const float*)d_in[3];
    float* OUT = (float*)d_out;

    char* base = (char*)d_ws;
    unsigned short* XNh = (unsigned short*)(base);               //  8,388,608 B
    unsigned short* XNl = (unsigned short*)(base + 8388608);     //  8,388,608 (dead after gemm1 -> KT)
    float*          PD  = (float*)(base + 16777216);             // 16,777,216 (dead after featvt -> PART)
    unsigned short* QR  = (unsigned short*)(base + 33554432);    //  8,388,608
    unsigned short* VT  = (unsigned short*)(base + 41943040);    //  8,388,608
    unsigned short* CT  = (unsigned short*)(base + 50331648);    //    524,288
    unsigned short* Ph  = (unsigned short*)(base + 50855936);    //    131,072
    unsigned short* Pl  = (unsigned short*)(base + 50987008);    //    131,072
    float*          diag = (float*)(base + 51118080);            //     65,536
    unsigned*       mxqI = (unsigned*)(base + 51183616);         //     65,536
    float*          mxqF = (float*)(base + 51249152);            //     65,536
    float*          mxk  = (float*)(base + 51314688);            //        256
    float*          KSUM = (float*)(base + 51314944);            //      4,096
    unsigned short* KT   = XNl;   // alias: XNl dead after gemm1
    float*          PART = PD;    // alias: PD dead after featvt

    k_splitp<<<32, 256, 0, stream>>>(P, Ph, Pl);
    k_ln<<<BSn / 4, 256, 0, stream>>>(X, gamma, beta, XNh, XNl, diag, mxqI);
    k_gemm1<<<dim3(BSn / 64, Mn / 128), 256, 0, stream>>>(XNh, XNl, Ph, Pl, PD, mxqI);
    k_batchmax<<<Bn, 256, 0, stream>>>(mxqI, mxqF, mxk, KSUM);
    k_featvt<<<dim3(Sn / 64, 4, 8), 256, 0, stream>>>(PD, XNh, diag, mxk, mxqF, KT, QR, VT, KSUM);
    k_gemm2<<<dim3(16, 4, Bn), 256, 0, stream>>>(VT, KT, PART);
    k_ctxred<<<256, 256, 0, stream>>>(PART, CT);
    k_gemm3<<<dim3(BSn / 64, Dn / 128), 256, 0, stream>>>(QR, CT, KSUM, OUT);
}